// Round 3
// baseline (114.095 us; speedup 1.0000x reference)
//
#include <hip/hip_runtime.h>
#include <hip/hip_bf16.h>
#include <stdint.h>

// Single attention head. B=4, T=2048, C=1024, H=64. FP32 in/out (proven).
// Outputs concat fp32: out[B,T,H], k[B,T,H], v[B,T,H]. scale = 1/32.
//
// R14 == R13 resubmitted (R13 never benched: GPU acquisition timeout).
//  - attn: one 512-thread block per complementary q-tile PAIR (qtA=x,
//    qtB=127-x): grid 64x4 = 256 blocks = 1/CU, uniform 33 tile-units/CU.
//    8 waves split proportionally between the two q-tiles (wA = round(
//    8*nA/33)), so the critical wave does ~5 k-tiles everywhere (was 8-9
//    on the worst CU with half its waves idle). Merge sums the wave-range
//    belonging to each q-tile. Per-tile math/layouts unchanged (proven).
//  - qkv/prep unchanged from R12 for attribution.
// ws (4 MB): [0) Wb 384KB; [1MB) qb; [2MB) kb; [3MB) vT (1MB each, bf16).

#define NB 4
#define TT 2048
#define CC 1024
#define HH 64
#define NKV (NB * TT * HH)

typedef __attribute__((ext_vector_type(8))) short short8; // 8 bf16 = 4 VGPRs
typedef __attribute__((ext_vector_type(4))) float f32x4;  // MFMA C/D

__device__ __forceinline__ unsigned short f2bf(float f) {
    union { float f; unsigned int i; } v;
    v.f = f;
    unsigned int r = v.i + 0x7fffu + ((v.i >> 16) & 1u); // RNE
    return (unsigned short)(r >> 16);
}
// packed RNE f32x2 -> bf16x2 (v_cvt_pk_bf16_f32 on gfx950)
__device__ __forceinline__ unsigned int pkbf2(float a, float b) {
    __hip_bfloat162 h = __float22bfloat162_rn(make_float2(a, b));
    union { __hip_bfloat162 h; unsigned int u; } c;
    c.h = h;
    return c.u;
}

// ---------------------------------------------------------------------------
// prep_wb (R9/R10-proven): Wb[((s*32+kk)*64 + l)*8 + j] =
// W_m[k = 32kk + (l>>4)*8 + j][h = (s&3)*16 + (l&15)], m = s>>2.
// ---------------------------------------------------------------------------
__global__ __launch_bounds__(256) void prep_wb(const float* __restrict__ Wq,
                                               const float* __restrict__ Wk,
                                               const float* __restrict__ Wv,
                                               unsigned short* __restrict__ Wb) {
    int gid = blockIdx.x * 256 + threadIdx.x; // 0 .. 196607
    int j  = gid & 7;
    int l  = (gid >> 3) & 63;
    int kk = (gid >> 9) & 31;
    int s  = gid >> 14;
    int k  = kk * 32 + (l >> 4) * 8 + j;
    int h  = (s & 3) * 16 + (l & 15);
    const float* W = (s >> 2) == 0 ? Wq : (s >> 2) == 1 ? Wk : Wv;
    Wb[gid] = f2bf(W[(size_t)k * HH + h]);
}

// ---------------------------------------------------------------------------
// qkv_mfma (R10-proven structure + packed cvt + SC2-folded qb).
// 512 blocks x 4 waves, 16 rows/block; x staged to LDS bf16 (stride 1032).
// Wave w computes frags s in {w, w+4, w+8} (q,k,v cols w*16..+15), full K.
// ---------------------------------------------------------------------------
#define XSTR 1032
#define SC2F 0.0450842200113808f // (1/32)*log2(e)

__global__ __launch_bounds__(256) void qkv_mfma(const float* __restrict__ x,
                                                const unsigned short* __restrict__ Wb,
                                                float* __restrict__ out,
                                                unsigned short* __restrict__ qb,
                                                unsigned short* __restrict__ kb,
                                                unsigned short* __restrict__ vT) {
    __shared__ __align__(16) unsigned short xs[16 * XSTR]; // 33KB
    const int t    = threadIdx.x;
    const int wave = t >> 6, lane = t & 63;
    const int n    = lane & 15, quad = lane >> 4;
    const int row0 = blockIdx.x * 16;
    const int b    = row0 >> 11;

    // stage x tile (16 rows x 1024) fp32 -> bf16, packed converts
#pragma unroll 8
    for (int i = 0; i < 16; ++i) {
        float4 f = *(const float4*)(x + (size_t)(row0 + i) * CC + 4 * t);
        uint2 u;
        u.x = pkbf2(f.x, f.y);
        u.y = pkbf2(f.z, f.w);
        *(uint2*)&xs[i * XSTR + 4 * t] = u;
    }
    __syncthreads();

    f32x4 acc0 = (f32x4){0.f, 0.f, 0.f, 0.f};
    f32x4 acc1 = acc0, acc2 = acc0;

    const unsigned short* wp = Wb + (size_t)lane * 8;
    const size_t fs = (size_t)32 * 64 * 8; // frag-s stride

#pragma unroll 4
    for (int kk = 0; kk < 32; ++kk) {
        short8 a = *(const short8*)&xs[n * XSTR + kk * 32 + quad * 8];
        const unsigned short* wk_ = wp + (size_t)kk * 512;
        short8 b0 = *(const short8*)(wk_ + (size_t)(wave)     * fs);
        short8 b1 = *(const short8*)(wk_ + (size_t)(wave + 4) * fs);
        short8 b2 = *(const short8*)(wk_ + (size_t)(wave + 8) * fs);
        acc0 = __builtin_amdgcn_mfma_f32_16x16x32_bf16(a, b0, acc0, 0, 0, 0);
        acc1 = __builtin_amdgcn_mfma_f32_16x16x32_bf16(a, b1, acc1, 0, 0, 0);
        acc2 = __builtin_amdgcn_mfma_f32_16x16x32_bf16(a, b2, acc2, 0, 0, 0);
    }

    // epilogue: C row = row0 + quad*4 + r, col h = wave*16 + n
    const int h = wave * 16 + n;
    const size_t g0 = (size_t)(row0 + quad * 4) * HH + h; // row r=0

    unsigned int uq01 = pkbf2(acc0[0] * SC2F, acc0[1] * SC2F);
    unsigned int uq23 = pkbf2(acc0[2] * SC2F, acc0[3] * SC2F);
    unsigned int uk01 = pkbf2(acc1[0], acc1[1]);
    unsigned int uk23 = pkbf2(acc1[2], acc1[3]);
    qb[g0]          = (unsigned short)uq01;
    qb[g0 + HH]     = (unsigned short)(uq01 >> 16);
    qb[g0 + 2 * HH] = (unsigned short)uq23;
    qb[g0 + 3 * HH] = (unsigned short)(uq23 >> 16);
    kb[g0]          = (unsigned short)uk01;
    kb[g0 + HH]     = (unsigned short)(uk01 >> 16);
    kb[g0 + 2 * HH] = (unsigned short)uk23;
    kb[g0 + 3 * HH] = (unsigned short)(uk23 >> 16);
#pragma unroll
    for (int r = 0; r < 4; ++r) {
        out[NKV + g0 + (size_t)r * HH]     = acc1[r];
        out[2 * NKV + g0 + (size_t)r * HH] = acc2[r];
    }
    // vT rows r=0..3 are consecutive t positions -> one b64 store
    uint2 uv;
    uv.x = pkbf2(acc2[0], acc2[1]);
    uv.y = pkbf2(acc2[2], acc2[3]);
    *(uint2*)&vT[(size_t)(b * HH + h) * TT + (row0 & 2047) + quad * 4] = uv;
}

// ---------------------------------------------------------------------------
// attn_mfma v5: static-max flash, pooled complementary q-tile pairs.
// Grid (64, 4) x 512 threads (8 waves). Block handles qtA = x (nA k-tiles)
// and qtB = 127-x (nB tiles), nA+nB = 33. Waves [0,wA) work qtA with stride
// wA; waves [wA,8) work qtB with stride 8-wA, wA = round(8*nA/33). Critical
// wave ~5 tiles (was 8-9), uniform across all 256 CUs.
// Per tile: batched K loads -> 8 QK MFMA -> V loads issued (hidden under
// exp/LDS) -> p = exp2(sc) -> P via wave-private LDS -> 8 PV MFMA.
// l deferred to one post-loop lane-reduction; per-q-tile merge sums that
// tile's wave range. Exactly one masked (diagonal) tile per q-tile.
// ---------------------------------------------------------------------------
__global__ __launch_bounds__(512) void attn_mfma(float* __restrict__ out,
                                                 const unsigned short* __restrict__ qb,
                                                 const unsigned short* __restrict__ kb,
                                                 const unsigned short* __restrict__ vT) {
    __shared__ __align__(16) unsigned short Ps[8][16][72]; // 18.4KB
    __shared__ float Lb[8][64][4];                         // 8KB
    __shared__ float Ob[8][64][16];                        // 32KB

    const int t    = threadIdx.x;
    const int wave = t >> 6, lane = t & 63;
    const int n    = lane & 15, quad = lane >> 4;
    const int b    = blockIdx.y;

    const int qtA = blockIdx.x;        // 0..63
    const int qtB = 127 - blockIdx.x;  // 64..127
    const int nA  = (qtA >> 2) + 1;
    const int nB  = (qtB >> 2) + 1;    // nA + nB == 33
    int wA = (8 * nA + 16) / 33;       // round(8*nA/33)
    wA = wA < 1 ? 1 : (wA > 7 ? 7 : wA);

    const int inA     = (wave < wA);
    const int qt      = inA ? qtA : qtB;
    const int kt0     = inA ? wave : wave - wA;
    const int kstride = inA ? wA : 8 - wA;
    const int nkt     = inA ? nA : nB;
    const int q0      = qt * 16;

    // Q A-fragments (pre-scaled by SC2): row = q0 + n
    const unsigned short* qr = qb + (size_t)(b * TT + q0 + n) * HH + quad * 8;
    short8 aq0 = *(const short8*)(qr);
    short8 aq1 = *(const short8*)(qr + 32);

    f32x4 oc[4];
#pragma unroll
    for (int d = 0; d < 4; ++d) oc[d] = (f32x4){0.f, 0.f, 0.f, 0.f};
    float l_[4] = {0.f, 0.f, 0.f, 0.f};

    for (int kt = kt0; kt < nkt; kt += kstride) {
        const int j0 = kt * 64;

        // ---- batched K fragment loads ----
        short8 bk0[4], bk1[4];
#pragma unroll
        for (int s = 0; s < 4; ++s) {
            const unsigned short* kr = kb + (size_t)(b * TT + j0 + s * 16 + n) * HH + quad * 8;
            bk0[s] = *(const short8*)(kr);
            bk1[s] = *(const short8*)(kr + 32);
        }

        // ---- V fragment loads issued NOW; consumed after exp/LDS phase ----
        short8 bv0[4], bv1[4];
#pragma unroll
        for (int d = 0; d < 4; ++d) {
            const unsigned short* vr = vT + (size_t)(b * HH + d * 16 + n) * TT + j0 + quad * 8;
            bv0[d] = *(const short8*)(vr);
            bv1[d] = *(const short8*)(vr + 32);
        }

        // ---- scores (base-2 logits; q pre-scaled) ----
        f32x4 sc[4];
#pragma unroll
        for (int s = 0; s < 4; ++s) sc[s] = (f32x4){0.f, 0.f, 0.f, 0.f};
        __builtin_amdgcn_s_setprio(1);
#pragma unroll
        for (int s = 0; s < 4; ++s) {
            sc[s] = __builtin_amdgcn_mfma_f32_16x16x32_bf16(aq0, bk0[s], sc[s], 0, 0, 0);
            sc[s] = __builtin_amdgcn_mfma_f32_16x16x32_bf16(aq1, bk1[s], sc[s], 0, 0, 0);
        }
        __builtin_amdgcn_s_setprio(0);

        // ---- p = exp2(sc), masked only on the (single) diagonal tile ----
        float p[4][4]; // [s][r]
        if (j0 + 63 <= q0) { // full tile (wave-uniform)
#pragma unroll
            for (int s = 0; s < 4; ++s)
#pragma unroll
                for (int r = 0; r < 4; ++r) {
                    float pe = exp2f(sc[s][r]);
                    p[s][r] = pe;
                    l_[r] += pe;
                }
        } else { // diagonal tile
#pragma unroll
            for (int r = 0; r < 4; ++r) {
                const int qrow = q0 + quad * 4 + r;
#pragma unroll
                for (int s = 0; s < 4; ++s) {
                    int krow = j0 + s * 16 + n;
                    float pe = (krow <= qrow) ? exp2f(sc[s][r]) : 0.f;
                    p[s][r] = pe;
                    l_[r] += pe;
                }
            }
        }

        // ---- P: C-layout -> wave-private LDS -> A-layout (proven R9/R10) ----
#pragma unroll
        for (int s = 0; s < 4; ++s) {
            unsigned int u01 = pkbf2(p[s][0], p[s][1]);
            unsigned int u23 = pkbf2(p[s][2], p[s][3]);
            Ps[wave][quad * 4 + 0][s * 16 + n] = (unsigned short)u01;
            Ps[wave][quad * 4 + 1][s * 16 + n] = (unsigned short)(u01 >> 16);
            Ps[wave][quad * 4 + 2][s * 16 + n] = (unsigned short)u23;
            Ps[wave][quad * 4 + 3][s * 16 + n] = (unsigned short)(u23 >> 16);
        }
        __asm__ volatile("s_waitcnt lgkmcnt(0)" ::: "memory");
        short8 ap0 = *(const short8*)&Ps[wave][n][quad * 8];
        short8 ap1 = *(const short8*)&Ps[wave][n][32 + quad * 8];

        // ---- O += P @ V (V already in registers) ----
        __builtin_amdgcn_s_setprio(1);
#pragma unroll
        for (int d = 0; d < 4; ++d) {
            oc[d] = __builtin_amdgcn_mfma_f32_16x16x32_bf16(ap0, bv0[d], oc[d], 0, 0, 0);
            oc[d] = __builtin_amdgcn_mfma_f32_16x16x32_bf16(ap1, bv1[d], oc[d], 0, 0, 0);
        }
        __builtin_amdgcn_s_setprio(0);
    }

    // ---- deferred l reduction across the 16 lanes sharing a row set ----
#pragma unroll
    for (int off = 1; off < 16; off <<= 1)
#pragma unroll
        for (int r = 0; r < 4; ++r)
            l_[r] += __shfl_xor(l_[r], off);

    // ---- cross-wave sum-merge (per q-tile wave range) ----
#pragma unroll
    for (int r = 0; r < 4; ++r) Lb[wave][lane][r] = l_[r];
#pragma unroll
    for (int d = 0; d < 4; ++d)
#pragma unroll
        for (int r = 0; r < 4; ++r)
            Ob[wave][lane][d * 4 + r] = oc[d][r];
    __syncthreads();

    if (wave == 0 || wave == wA) {
        const int w0 = (wave == 0) ? 0 : wA;
        const int w1 = (wave == 0) ? wA : 8;
        const int qm = (wave == 0) ? qtA : qtB;
        const int qb0 = qm * 16;
#pragma unroll
        for (int r = 0; r < 4; ++r) {
            float ls = 0.f;
            for (int w = w0; w < w1; ++w) ls += Lb[w][lane][r];
            const float inv = 1.f / ls;
#pragma unroll
            for (int d = 0; d < 4; ++d) {
                float o = 0.f;
                for (int w = w0; w < w1; ++w) o += Ob[w][lane][d * 4 + r];
                out[(size_t)(b * TT + qb0 + quad * 4 + r) * HH + d * 16 + n] = o * inv;
            }
        }
    }
}

// ---------------------------------------------------------------------------
extern "C" void kernel_launch(void* const* d_in, const int* in_sizes, int n_in,
                              void* d_out, int out_size, void* d_ws, size_t ws_size,
                              hipStream_t stream) {
    const float* x  = (const float*)d_in[0];
    const float* Wq = (const float*)d_in[1];
    const float* Wk = (const float*)d_in[2];
    const float* Wv = (const float*)d_in[3];
    float* out = (float*)d_out;

    char* ws = (char*)d_ws;
    unsigned short* Wb = (unsigned short*)(ws);              // 384 KB
    unsigned short* qb = (unsigned short*)(ws + (1u << 20)); // 1 MB
    unsigned short* kb = (unsigned short*)(ws + (2u << 20)); // 1 MB
    unsigned short* vT = (unsigned short*)(ws + (3u << 20)); // 1 MB

    prep_wb<<<768, 256, 0, stream>>>(Wq, Wk, Wv, Wb);
    qkv_mfma<<<512, 256, 0, stream>>>(x, Wb, out, qb, kb, vT);
    attn_mfma<<<dim3(64, 4), 512, 0, stream>>>(out, qb, kb, vT);
}

// Round 4
// 106.919 us; speedup vs baseline: 1.0671x; 1.0671x over previous
//
#include <hip/hip_runtime.h>
#include <hip/hip_bf16.h>
#include <stdint.h>

// Single attention head. B=4, T=2048, C=1024, H=64. FP32 in/out (proven).
// Outputs concat fp32: out[B,T,H], k[B,T,H], v[B,T,H]. scale = 1/32.
//
// R15 = attn reverted to R12-exact (107.4us proven; R14 pooled-pair attn
// regressed to 114.1 and is abandoned) + qkv restructured for Wb L2 reuse:
//  - qkv: 256 blocks x 512 threads, 32 rows/block. Wave w: row-tile rt=w>>2,
//    frag set fw=w&3. Same Wb bytes feed 2x rows -> Wb L2 traffic 192->96MB;
//    waves w/w+4 share frags -> L1 temporal hits. LDS = exactly 64KB via
//    XOR swizzle on 8B units (u ^= (row&7)<<1), write+read both swizzled;
//    per-quarter-wave 2-way bank access (free), same as the old 1032-pad.
//  - attn/prep unchanged from R12 for attribution.
// ws (4 MB): [0) Wb 384KB; [1MB) qb; [2MB) kb; [3MB) vT (1MB each, bf16).

#define NB 4
#define TT 2048
#define CC 1024
#define HH 64
#define NKV (NB * TT * HH)

typedef __attribute__((ext_vector_type(8))) short short8; // 8 bf16 = 4 VGPRs
typedef __attribute__((ext_vector_type(4))) float f32x4;  // MFMA C/D

__device__ __forceinline__ unsigned short f2bf(float f) {
    union { float f; unsigned int i; } v;
    v.f = f;
    unsigned int r = v.i + 0x7fffu + ((v.i >> 16) & 1u); // RNE
    return (unsigned short)(r >> 16);
}
// packed RNE f32x2 -> bf16x2 (v_cvt_pk_bf16_f32 on gfx950)
__device__ __forceinline__ unsigned int pkbf2(float a, float b) {
    __hip_bfloat162 h = __float22bfloat162_rn(make_float2(a, b));
    union { __hip_bfloat162 h; unsigned int u; } c;
    c.h = h;
    return c.u;
}

// ---------------------------------------------------------------------------
// prep_wb (R9/R10-proven): Wb[((s*32+kk)*64 + l)*8 + j] =
// W_m[k = 32kk + (l>>4)*8 + j][h = (s&3)*16 + (l&15)], m = s>>2.
// ---------------------------------------------------------------------------
__global__ __launch_bounds__(256) void prep_wb(const float* __restrict__ Wq,
                                               const float* __restrict__ Wk,
                                               const float* __restrict__ Wv,
                                               unsigned short* __restrict__ Wb) {
    int gid = blockIdx.x * 256 + threadIdx.x; // 0 .. 196607
    int j  = gid & 7;
    int l  = (gid >> 3) & 63;
    int kk = (gid >> 9) & 31;
    int s  = gid >> 14;
    int k  = kk * 32 + (l >> 4) * 8 + j;
    int h  = (s & 3) * 16 + (l & 15);
    const float* W = (s >> 2) == 0 ? Wq : (s >> 2) == 1 ? Wk : Wv;
    Wb[gid] = f2bf(W[(size_t)k * HH + h]);
}

// ---------------------------------------------------------------------------
// qkv_mfma v2: 256 blocks x 512 threads, 32 rows/block, 8 waves.
// Wave w: row-tile rt = w>>2 (rows row0+rt*16 .. +15), frag set fw = w&3
// (cols fw*16..+15 of q,k,v). Per kk: 3 Wb loads + 3 MFMA (same per-wave
// stream as R12; block covers 2x rows per Wb byte). x staged to LDS bf16,
// 32x1024, XOR-swizzled on 8B units: phys_u = u ^ ((row&7)<<1).
// ---------------------------------------------------------------------------
#define SC2F 0.0450842200113808f // (1/32)*log2(e)

__global__ __launch_bounds__(512) void qkv_mfma(const float* __restrict__ x,
                                                const unsigned short* __restrict__ Wb,
                                                float* __restrict__ out,
                                                unsigned short* __restrict__ qb,
                                                unsigned short* __restrict__ kb,
                                                unsigned short* __restrict__ vT) {
    __shared__ __align__(16) unsigned short xs[32 * 1024]; // 64KB exactly
    const int t    = threadIdx.x;
    const int wave = t >> 6, lane = t & 63;
    const int n    = lane & 15, quad = lane >> 4;
    const int fw   = wave & 3, rt = wave >> 2;
    const int row0 = blockIdx.x * 32;
    const int b    = row0 >> 11;

    // stage x tile (32 rows x 1024) fp32 -> bf16, swizzled write
    {
        const int tr = t >> 8, tc = t & 255; // tc = 8B unit within row
#pragma unroll 8
        for (int it = 0; it < 16; ++it) {
            const int i = it * 2 + tr;
            float4 f = *(const float4*)(x + (size_t)(row0 + i) * CC + 4 * tc);
            uint2 u;
            u.x = pkbf2(f.x, f.y);
            u.y = pkbf2(f.z, f.w);
            *(uint2*)&xs[i * 1024 + ((tc ^ ((i & 7) << 1)) << 2)] = u;
        }
    }
    __syncthreads();

    f32x4 acc0 = (f32x4){0.f, 0.f, 0.f, 0.f};
    f32x4 acc1 = acc0, acc2 = acc0;

    const unsigned short* wp = Wb + (size_t)lane * 8;
    const size_t fs = (size_t)32 * 64 * 8; // frag-s stride
    const int arow = (rt * 16 + n) * 1024;
    const int axor = (n & 7) << 1;

#pragma unroll 4
    for (int kk = 0; kk < 32; ++kk) {
        short8 a = *(const short8*)&xs[arow + (((kk * 8 + quad * 2) ^ axor) << 2)];
        const unsigned short* wk_ = wp + (size_t)kk * 512;
        short8 b0 = *(const short8*)(wk_ + (size_t)(fw)     * fs);
        short8 b1 = *(const short8*)(wk_ + (size_t)(fw + 4) * fs);
        short8 b2 = *(const short8*)(wk_ + (size_t)(fw + 8) * fs);
        acc0 = __builtin_amdgcn_mfma_f32_16x16x32_bf16(a, b0, acc0, 0, 0, 0);
        acc1 = __builtin_amdgcn_mfma_f32_16x16x32_bf16(a, b1, acc1, 0, 0, 0);
        acc2 = __builtin_amdgcn_mfma_f32_16x16x32_bf16(a, b2, acc2, 0, 0, 0);
    }

    // epilogue: C row = row0 + rt*16 + quad*4 + r, col h = fw*16 + n
    const int h = fw * 16 + n;
    const size_t g0 = (size_t)(row0 + rt * 16 + quad * 4) * HH + h; // row r=0

    unsigned int uq01 = pkbf2(acc0[0] * SC2F, acc0[1] * SC2F);
    unsigned int uq23 = pkbf2(acc0[2] * SC2F, acc0[3] * SC2F);
    unsigned int uk01 = pkbf2(acc1[0], acc1[1]);
    unsigned int uk23 = pkbf2(acc1[2], acc1[3]);
    qb[g0]          = (unsigned short)uq01;
    qb[g0 + HH]     = (unsigned short)(uq01 >> 16);
    qb[g0 + 2 * HH] = (unsigned short)uq23;
    qb[g0 + 3 * HH] = (unsigned short)(uq23 >> 16);
    kb[g0]          = (unsigned short)uk01;
    kb[g0 + HH]     = (unsigned short)(uk01 >> 16);
    kb[g0 + 2 * HH] = (unsigned short)uk23;
    kb[g0 + 3 * HH] = (unsigned short)(uk23 >> 16);
#pragma unroll
    for (int r = 0; r < 4; ++r) {
        out[NKV + g0 + (size_t)r * HH]     = acc1[r];
        out[2 * NKV + g0 + (size_t)r * HH] = acc2[r];
    }
    // vT rows r=0..3 are consecutive t positions -> one b64 store
    uint2 uv;
    uv.x = pkbf2(acc2[0], acc2[1]);
    uv.y = pkbf2(acc2[2], acc2[3]);
    *(uint2*)&vT[(size_t)(b * HH + h) * TT + ((row0 + rt * 16) & 2047) + quad * 4] = uv;
}

// ---------------------------------------------------------------------------
// attn_mfma (R12-exact, 107.4us proven): static-max flash. Grid (128 x-tiles,
// 4 batches) x 4 waves; qt = (b<2) ? x : 127-x so CU-co-resident blocks have
// complementary causal work. Waves split K-tiles (kt = w mod 4). Per tile:
// batched K loads -> 8 QK MFMA -> V loads issued (hidden under exp/LDS) ->
// p = exp2(sc) -> P via wave-private LDS -> 8 PV MFMA. l deferred to one
// post-loop lane-reduction; cross-wave merge is a plain sum. Exactly one
// masked (diagonal) tile per q-tile.
// ---------------------------------------------------------------------------
__global__ __launch_bounds__(256) void attn_mfma(float* __restrict__ out,
                                                 const unsigned short* __restrict__ qb,
                                                 const unsigned short* __restrict__ kb,
                                                 const unsigned short* __restrict__ vT) {
    __shared__ __align__(16) unsigned short Ps[4][16][72]; // 9.2KB
    __shared__ float Lb[4][64][4];                         // 4KB
    __shared__ float Ob[4][64][16];                        // 16KB

    const int t    = threadIdx.x;
    const int wave = t >> 6, lane = t & 63;
    const int n    = lane & 15, quad = lane >> 4;
    const int b    = blockIdx.y;
    const int qt   = (b < 2) ? blockIdx.x : 127 - blockIdx.x; // balance remap
    const int q0   = qt * 16;

    // Q A-fragments (pre-scaled by SC2): row = q0 + n
    const unsigned short* qr = qb + (size_t)(b * TT + q0 + n) * HH + quad * 8;
    short8 aq0 = *(const short8*)(qr);
    short8 aq1 = *(const short8*)(qr + 32);

    f32x4 oc[4];
#pragma unroll
    for (int d = 0; d < 4; ++d) oc[d] = (f32x4){0.f, 0.f, 0.f, 0.f};
    float l_[4] = {0.f, 0.f, 0.f, 0.f};

    const int nkt = (q0 >> 6) + 1;

    for (int kt = wave; kt < nkt; kt += 4) {
        const int j0 = kt * 64;

        // ---- batched K fragment loads ----
        short8 bk0[4], bk1[4];
#pragma unroll
        for (int s = 0; s < 4; ++s) {
            const unsigned short* kr = kb + (size_t)(b * TT + j0 + s * 16 + n) * HH + quad * 8;
            bk0[s] = *(const short8*)(kr);
            bk1[s] = *(const short8*)(kr + 32);
        }

        // ---- V fragment loads issued NOW; consumed after exp/LDS phase ----
        short8 bv0[4], bv1[4];
#pragma unroll
        for (int d = 0; d < 4; ++d) {
            const unsigned short* vr = vT + (size_t)(b * HH + d * 16 + n) * TT + j0 + quad * 8;
            bv0[d] = *(const short8*)(vr);
            bv1[d] = *(const short8*)(vr + 32);
        }

        // ---- scores (base-2 logits; q pre-scaled) ----
        f32x4 sc[4];
#pragma unroll
        for (int s = 0; s < 4; ++s) sc[s] = (f32x4){0.f, 0.f, 0.f, 0.f};
        __builtin_amdgcn_s_setprio(1);
#pragma unroll
        for (int s = 0; s < 4; ++s) {
            sc[s] = __builtin_amdgcn_mfma_f32_16x16x32_bf16(aq0, bk0[s], sc[s], 0, 0, 0);
            sc[s] = __builtin_amdgcn_mfma_f32_16x16x32_bf16(aq1, bk1[s], sc[s], 0, 0, 0);
        }
        __builtin_amdgcn_s_setprio(0);

        // ---- p = exp2(sc), masked only on the (single) diagonal tile ----
        float p[4][4]; // [s][r]
        if (j0 + 63 <= q0) { // full tile (wave-uniform)
#pragma unroll
            for (int s = 0; s < 4; ++s)
#pragma unroll
                for (int r = 0; r < 4; ++r) {
                    float pe = exp2f(sc[s][r]);
                    p[s][r] = pe;
                    l_[r] += pe;
                }
        } else { // diagonal tile
#pragma unroll
            for (int r = 0; r < 4; ++r) {
                const int qrow = q0 + quad * 4 + r;
#pragma unroll
                for (int s = 0; s < 4; ++s) {
                    int krow = j0 + s * 16 + n;
                    float pe = (krow <= qrow) ? exp2f(sc[s][r]) : 0.f;
                    p[s][r] = pe;
                    l_[r] += pe;
                }
            }
        }

        // ---- P: C-layout -> wave-private LDS -> A-layout (proven R9/R10) ----
#pragma unroll
        for (int s = 0; s < 4; ++s) {
            unsigned int u01 = pkbf2(p[s][0], p[s][1]);
            unsigned int u23 = pkbf2(p[s][2], p[s][3]);
            Ps[wave][quad * 4 + 0][s * 16 + n] = (unsigned short)u01;
            Ps[wave][quad * 4 + 1][s * 16 + n] = (unsigned short)(u01 >> 16);
            Ps[wave][quad * 4 + 2][s * 16 + n] = (unsigned short)u23;
            Ps[wave][quad * 4 + 3][s * 16 + n] = (unsigned short)(u23 >> 16);
        }
        __asm__ volatile("s_waitcnt lgkmcnt(0)" ::: "memory");
        short8 ap0 = *(const short8*)&Ps[wave][n][quad * 8];
        short8 ap1 = *(const short8*)&Ps[wave][n][32 + quad * 8];

        // ---- O += P @ V (V already in registers) ----
        __builtin_amdgcn_s_setprio(1);
#pragma unroll
        for (int d = 0; d < 4; ++d) {
            oc[d] = __builtin_amdgcn_mfma_f32_16x16x32_bf16(ap0, bv0[d], oc[d], 0, 0, 0);
            oc[d] = __builtin_amdgcn_mfma_f32_16x16x32_bf16(ap1, bv1[d], oc[d], 0, 0, 0);
        }
        __builtin_amdgcn_s_setprio(0);
    }

    // ---- deferred l reduction across the 16 lanes sharing a row set ----
#pragma unroll
    for (int off = 1; off < 16; off <<= 1)
#pragma unroll
        for (int r = 0; r < 4; ++r)
            l_[r] += __shfl_xor(l_[r], off);

    // ---- cross-wave sum-merge ----
#pragma unroll
    for (int r = 0; r < 4; ++r) Lb[wave][lane][r] = l_[r];
#pragma unroll
    for (int d = 0; d < 4; ++d)
#pragma unroll
        for (int r = 0; r < 4; ++r)
            Ob[wave][lane][d * 4 + r] = oc[d][r];
    __syncthreads();

    if (wave == 0) {
#pragma unroll
        for (int r = 0; r < 4; ++r) {
            float ls = Lb[0][lane][r] + Lb[1][lane][r] + Lb[2][lane][r] + Lb[3][lane][r];
            const float inv = 1.f / ls;
#pragma unroll
            for (int d = 0; d < 4; ++d) {
                float o = Ob[0][lane][d * 4 + r] + Ob[1][lane][d * 4 + r] +
                          Ob[2][lane][d * 4 + r] + Ob[3][lane][d * 4 + r];
                out[(size_t)(b * TT + q0 + quad * 4 + r) * HH + d * 16 + n] = o * inv;
            }
        }
    }
}

// ---------------------------------------------------------------------------
extern "C" void kernel_launch(void* const* d_in, const int* in_sizes, int n_in,
                              void* d_out, int out_size, void* d_ws, size_t ws_size,
                              hipStream_t stream) {
    const float* x  = (const float*)d_in[0];
    const float* Wq = (const float*)d_in[1];
    const float* Wk = (const float*)d_in[2];
    const float* Wv = (const float*)d_in[3];
    float* out = (float*)d_out;

    char* ws = (char*)d_ws;
    unsigned short* Wb = (unsigned short*)(ws);              // 384 KB
    unsigned short* qb = (unsigned short*)(ws + (1u << 20)); // 1 MB
    unsigned short* kb = (unsigned short*)(ws + (2u << 20)); // 1 MB
    unsigned short* vT = (unsigned short*)(ws + (3u << 20)); // 1 MB

    prep_wb<<<768, 256, 0, stream>>>(Wq, Wk, Wv, Wb);
    qkv_mfma<<<256, 512, 0, stream>>>(x, Wb, out, qb, kb, vT);
    attn_mfma<<<dim3(128, 4), 256, 0, stream>>>(out, qb, kb, vT);
}